// Round 16
// baseline (4047.069 us; speedup 1.0000x reference)
//
#include <hip/hip_runtime.h>
#include <hip/hip_bf16.h>

// ---------- types / helpers ----------
typedef __bf16 bf16x8 __attribute__((ext_vector_type(8)));
typedef float  f32x4  __attribute__((ext_vector_type(4)));
typedef _Float16 h16x8 __attribute__((ext_vector_type(8)));

__device__ __forceinline__ unsigned short f2b(float f) {
    union { float f; unsigned u; } w; w.f = f;
    unsigned u = w.u + 0x7FFF + ((w.u >> 16) & 1);
    return (unsigned short)(u >> 16);
}
__device__ __forceinline__ float b2f(unsigned short s) {
    union { unsigned u; float f; } w; w.u = ((unsigned)s) << 16; return w.f;
}
__device__ __forceinline__ float tanhfast(float x) {
    float e = __expf(2.0f * x);
    return 1.0f - 2.0f / (e + 1.0f);
}

// AGENT-scope write-through stores for per-step state; readers plain loads
// (fresh-slot discipline).
__device__ __forceinline__ void stU(unsigned* p, unsigned v) {
    __hip_atomic_store(p, v, __ATOMIC_RELAXED, __HIP_MEMORY_SCOPE_AGENT);
}
__device__ __forceinline__ int ldI(const int* p) {
    return __hip_atomic_load((int*)p, __ATOMIC_RELAXED, __HIP_MEMORY_SCOPE_AGENT);
}
__device__ __forceinline__ void stI(int* p, int v) {
    __hip_atomic_store(p, v, __ATOMIC_RELAXED, __HIP_MEMORY_SCOPE_AGENT);
}

#define GLD16(g, l) __builtin_amdgcn_global_load_lds( \
    (const __attribute__((address_space(1))) void*)(g), \
    (__attribute__((address_space(3))) void*)(l), 16, 0, 0)

#define SLOT_STRIDE 16
#define NPOLL 256

// tree grid barrier (256 blocks)
__device__ __forceinline__ void gbar(int* slots, int* gen, int target) {
    asm volatile("s_waitcnt vmcnt(0)" ::: "memory");
    __syncthreads();
    if (blockIdx.x == 0) {
        if (threadIdx.x == 0) stI(slots, target);
        if (threadIdx.x < NPOLL) {
            while (ldI(slots + threadIdx.x * SLOT_STRIDE) < target)
                __builtin_amdgcn_s_sleep(1);
        }
        __syncthreads();
        if (threadIdx.x == 0) stI(gen, target);
    } else {
        if (threadIdx.x == 0) {
            stI(slots + blockIdx.x * SLOT_STRIDE, target);
            while (ldI(gen) < target)
                __builtin_amdgcn_s_sleep(1);
        }
        __syncthreads();
    }
}

// 16-deep load batch + 16 MFMAs. B from LDS K-major ([k8][16 rows] bf16x8).
__device__ __forceinline__ void mac16L(const unsigned short* A, const bf16x8* BL,
                                       f32x4& acc) {
    bf16x8 a[16];
#pragma unroll
    for (int kk = 0; kk < 16; ++kk) a[kk] = *(const bf16x8*)(A + kk * 32);
#pragma unroll
    for (int kk = 0; kk < 16; ++kk)
        acc = __builtin_amdgcn_mfma_f32_16x16x32_bf16(a[kk], BL[kk * 64], acc, 0, 0, 0);
}

// ---------- elementwise / conversion kernels ----------

__global__ void k_gather(const float* __restrict__ emb, const int* __restrict__ tok,
                         unsigned short* __restrict__ out, int L, int ldtok) {
    long total = (long)L * 64 * 128;
    for (long i = (long)blockIdx.x * blockDim.x + threadIdx.x; i < total;
         i += (long)gridDim.x * blockDim.x) {
        int  e4 = (int)(i & 127);
        long r  = i >> 7;
        int  t  = (int)(r >> 6), b = (int)(r & 63);
        int  tk = tok[b * ldtok + t];
        float4 v = *(const float4*)(emb + (long)tk * 512 + e4 * 4);
        ushort4 o; o.x = f2b(v.x); o.y = f2b(v.y); o.z = f2b(v.z); o.w = f2b(v.w);
        *(ushort4*)(out + r * 512 + e4 * 4) = o;
    }
}

__global__ void k_conv(const float* __restrict__ in, unsigned short* __restrict__ out,
                       long N_, int K_, int ldin, int col0, int ldout, int outcol0, int reorder) {
    long total = N_ * (K_ >> 2);
    int kq = K_ >> 2;
    for (long i = (long)blockIdx.x * blockDim.x + threadIdx.x; i < total;
         i += (long)gridDim.x * blockDim.x) {
        long n = i / kq;
        int  k4 = (int)(i - n * kq) * 4;
        long row = reorder ? (long)((n & 3) * 1024 + (n >> 2)) : n;
        float4 v = *(const float4*)(in + row * ldin + col0 + k4);
        ushort4 o; o.x = f2b(v.x); o.y = f2b(v.y); o.z = f2b(v.z); o.w = f2b(v.w);
        *(ushort4*)(out + n * ldout + outcol0 + k4) = o;
    }
}

// f32 -> fp16 (no reorder)
__global__ void k_conv16(const float* __restrict__ in, _Float16* __restrict__ out,
                         long N_, int K_, int ldin, int col0) {
    long total = N_ * (K_ >> 2);
    int kq = K_ >> 2;
    for (long i = (long)blockIdx.x * blockDim.x + threadIdx.x; i < total;
         i += (long)gridDim.x * blockDim.x) {
        long n = i / kq;
        int  k4 = (int)(i - n * kq) * 4;
        float4 v = *(const float4*)(in + n * ldin + col0 + k4);
        _Float16* o = out + n * K_ + k4;
        o[0] = (_Float16)v.x; o[1] = (_Float16)v.y;
        o[2] = (_Float16)v.z; o[3] = (_Float16)v.w;
    }
}

__global__ void k_bias(const float* __restrict__ b1, const float* __restrict__ b2,
                       float* __restrict__ out) {
    int n = blockIdx.x * blockDim.x + threadIdx.x;
    if (n < 4096) {
        int row = (n & 3) * 1024 + (n >> 2);
        out[n] = b1[row] + b2[row];
    }
}

__global__ void k_zero0(float* __restrict__ out) {
    long total = 64L * 8000;
    for (long i = (long)blockIdx.x * blockDim.x + threadIdx.x; i < total;
         i += (long)gridDim.x * blockDim.x) {
        int b = (int)(i / 8000), q = (int)(i % 8000);
        float4 z = {0.f, 0.f, 0.f, 0.f};
        *(float4*)(out + (long)b * 1024000 + q * 4) = z;
    }
}

// ---------- big-GEMM (prep + proj), m97 structure ----------
template<int BM, int BN, int WGM, int WGN, int FM, int FN>
__device__ __forceinline__ void gemm_core(
    const unsigned short* __restrict__ A, int lda,
    const unsigned short* __restrict__ B, int ldb,
    long m0, long n0, int K,
    unsigned short* As, unsigned short* Bs,
    f32x4 (&acc)[FM][FN])
{
    const int tid  = threadIdx.x;
    const int lane = tid & 63;
    const int wave = tid >> 6;
    const int wm = wave / WGN;
    const int wn = wave % WGN;
    const int srow = lane >> 2;
    const int scol = (lane & 3) * 8;
    const int frow = lane & 15;
    const int fcol = (lane >> 4) * 8;

    for (int k0 = 0; k0 < K; k0 += 32) {
        __syncthreads();
        for (int c = wave; c < BM / 16; c += 4) {
            const unsigned short* g = A + (m0 + c * 16 + srow) * (long)lda + k0 + scol;
            GLD16(g, As + c * 512);
        }
        for (int c = wave; c < BN / 16; c += 4) {
            const unsigned short* g = B + (n0 + c * 16 + srow) * (long)ldb + k0 + scol;
            GLD16(g, Bs + c * 512);
        }
        __syncthreads();
        bf16x8 af[FM], bfr[FN];
#pragma unroll
        for (int m = 0; m < FM; ++m)
            af[m] = *(const bf16x8*)(As + ((wm * FM + m) * 16 + frow) * 32 + fcol);
#pragma unroll
        for (int n = 0; n < FN; ++n)
            bfr[n] = *(const bf16x8*)(Bs + ((wn * FN + n) * 16 + frow) * 32 + fcol);
#pragma unroll
        for (int m = 0; m < FM; ++m)
#pragma unroll
            for (int n = 0; n < FN; ++n)
                acc[m][n] = __builtin_amdgcn_mfma_f32_16x16x32_bf16(af[m], bfr[n], acc[m][n], 0, 0, 0);
    }
}

// MODE 0: f32 out. MODE 2: fp16 out.
template<int BM, int BN, int WGM, int WGN, int FM, int FN, int MODE>
__global__ __launch_bounds__(256) void k_gemm(
    const unsigned short* __restrict__ A, int lda,
    const unsigned short* __restrict__ B, int ldb,
    float* __restrict__ C, long ldc, const float* __restrict__ bias,
    int M, int N, int K, int Mreal)
{
    __shared__ __align__(16) unsigned short As[BM * 32];
    __shared__ __align__(16) unsigned short Bs[BN * 32];
    long m0 = (long)blockIdx.y * BM;
    long n0 = (long)blockIdx.x * BN;
    f32x4 acc[FM][FN] = {};
    gemm_core<BM, BN, WGM, WGN, FM, FN>(A, lda, B, ldb, m0, n0, K, As, Bs, acc);

    const int lane = threadIdx.x & 63;
    const int wave = threadIdx.x >> 6;
    const int wm = wave / WGN, wn = wave % WGN;
#pragma unroll
    for (int n = 0; n < FN; ++n) {
        long col = n0 + wn * FN * 16 + n * 16 + (lane & 15);
        float bv = bias ? bias[col] : 0.0f;
#pragma unroll
        for (int m = 0; m < FM; ++m) {
            int rl = wm * FM * 16 + m * 16 + (lane >> 4) * 4;
#pragma unroll
            for (int q = 0; q < 4; ++q) {
                long r = m0 + rl + q;
                float val = acc[m][n][q] + bv;
                if (MODE == 0) {
                    C[r * ldc + col] = val;
                } else {
                    ((_Float16*)C)[r * ldc + col] = (_Float16)val;
                }
            }
        }
    }
}

// ---------- fc GEMM: 2-phase double-buffered, XCD-grouped ----------
template<int BM, int BN, int WGN, int FM, int FN>
__global__ __launch_bounds__(256) void k_fc(
    const unsigned short* __restrict__ A, int lda,
    const unsigned short* __restrict__ B, int ldb,
    float* __restrict__ C, long ldc, const float* __restrict__ bias,
    int K, int Mreal)
{
    __shared__ __align__(16) unsigned short As[2][BM * 32];
    __shared__ __align__(16) unsigned short Bs[2][BN * 32];
    int bid = blockIdx.x;
    int n = (bid & 7) * 32 + (bid >> 7);
    int m = (bid >> 3) & 15;
    if (n >= 250) return;
    long m0 = (long)m * BM, n0 = (long)n * BN;
    const int tid = threadIdx.x, lane = tid & 63, wave = tid >> 6;
    const int wm = wave / WGN, wn = wave % WGN;
    const int srow = lane >> 2, scol = (lane & 3) * 8;
    const int frow = lane & 15, fcol = (lane >> 4) * 8;
    f32x4 acc[FM][FN] = {};

#define FC_STAGE(buf, k0) \
    { for (int c = wave; c < BM / 16; c += 4) \
          GLD16(A + (m0 + c * 16 + srow) * (long)lda + (k0) + scol, As[buf] + c * 512); \
      for (int c = wave; c < BN / 16; c += 4) \
          GLD16(B + (n0 + c * 16 + srow) * (long)ldb + (k0) + scol, Bs[buf] + c * 512); }

    FC_STAGE(0, 0);
    asm volatile("s_waitcnt vmcnt(0)" ::: "memory");
    __syncthreads();
    const int NT = K / 32;
    for (int t = 0; t < NT; ++t) {
        int cur = t & 1;
        if (t + 1 < NT) FC_STAGE(cur ^ 1, (t + 1) * 32);
        bf16x8 af[FM], bfr[FN];
#pragma unroll
        for (int mm = 0; mm < FM; ++mm)
            af[mm] = *(const bf16x8*)(As[cur] + ((wm * FM + mm) * 16 + frow) * 32 + fcol);
#pragma unroll
        for (int nn = 0; nn < FN; ++nn)
            bfr[nn] = *(const bf16x8*)(Bs[cur] + ((wn * FN + nn) * 16 + frow) * 32 + fcol);
#pragma unroll
        for (int mm = 0; mm < FM; ++mm)
#pragma unroll
            for (int nn = 0; nn < FN; ++nn)
                acc[mm][nn] = __builtin_amdgcn_mfma_f32_16x16x32_bf16(af[mm], bfr[nn], acc[mm][nn], 0, 0, 0);
        asm volatile("s_waitcnt vmcnt(0)" ::: "memory");
        __syncthreads();
    }
#undef FC_STAGE
#pragma unroll
    for (int nn = 0; nn < FN; ++nn) {
        long col = n0 + wn * FN * 16 + nn * 16 + (lane & 15);
        float bv = bias[col];
#pragma unroll
        for (int mm = 0; mm < FM; ++mm) {
            int rl = wm * FM * 16 + mm * 16 + (lane >> 4) * 4;
#pragma unroll
            for (int q = 0; q < 4; ++q) {
                long r = m0 + rl + q;
                if (r < Mreal) {
                    long orow = (r & 63) * 32 + (r >> 6) + 1;
                    C[orow * ldc + col] = acc[mm][nn][q] + bv;
                }
            }
        }
    }
}

// ---------- persistent encoder (unchanged from r12) ----------
__global__ __launch_bounds__(512, 2) void k_enc(
    const unsigned short* __restrict__ W,
    const float* __restrict__ pre,
    unsigned short* __restrict__ hsl,
    unsigned short* __restrict__ enc_out,
    unsigned short* __restrict__ eoT,
    unsigned short* __restrict__ hS0,
    float* __restrict__ cspill,
    int* slots, int* gen)
{
    __shared__ __align__(16) unsigned short WL[16 * 1024];
    __shared__ float gs[64 * 16];
    const int blk = blockIdx.x, tid = threadIdx.x;
    const int lane = tid & 63, wave = tid >> 6;
    const int rt = wave >> 1, kh = wave & 1;
    const int n0 = blk * 16;
    const int grow = (rt * 16 + (lane >> 4) * 4) * 16 + (lane & 15);
    const int pb = tid >> 1, pjl = (tid & 1) * 2;
    const int jg = blk * 4 + pjl;
    for (int i = tid; i < 2048; i += 512) {
        int r = i & 15, k8 = i >> 4;
        ((bf16x8*)WL)[k8 * 16 + r] = *(const bf16x8*)(W + (long)(n0 + r) * 1024 + k8 * 8);
    }
    const bf16x8* BL = (const bf16x8*)WL + ((long)kh * 64 + (lane >> 4)) * 16 + (lane & 15);
    float c0 = 0.f, c1 = 0.f;
    float4 pr0 = {}, pr1 = {};
    if (tid < 128) {
        pr0 = *(const float4*)(pre + (long)pb * 4096 + n0 + pjl * 4);
        pr1 = *(const float4*)(pre + (long)pb * 4096 + n0 + pjl * 4 + 4);
    }
    __syncthreads();
    int bt = 0;
    for (int t = 0; t < 64; ++t) {
        const unsigned short* Ar = hsl + (long)t * 65536
            + (long)(rt * 16 + (lane & 15)) * 1024 + kh * 512 + (lane >> 4) * 8;
        f32x4 acc = {};
        mac16L(Ar, BL, acc);
        if (kh == 0) {
#pragma unroll
            for (int q = 0; q < 4; ++q) gs[grow + q * 16] = acc[q];
        }
        __syncthreads();
        if (kh == 1) {
#pragma unroll
            for (int q = 0; q < 4; ++q) atomicAdd(&gs[grow + q * 16], acc[q]);
        }
        __syncthreads();
        if (tid < 128) {
            float4 gA = *(const float4*)(gs + pb * 16 + pjl * 4);
            float4 gB = *(const float4*)(gs + pb * 16 + pjl * 4 + 4);
            float h0v, h1v;
            {
                float gi = gA.x + pr0.x, gf = gA.y + pr0.y, gg = gA.z + pr0.z, go = gA.w + pr0.w;
                float i_ = 1.f / (1.f + __expf(-gi)), f_ = 1.f / (1.f + __expf(-gf));
                float g_ = tanhfast(gg), o_ = 1.f / (1.f + __expf(-go));
                c0 = f_ * c0 + i_ * g_; h0v = o_ * tanhfast(c0);
            }
            {
                float gi = gB.x + pr1.x, gf = gB.y + pr1.y, gg = gB.z + pr1.z, go = gB.w + pr1.w;
                float i_ = 1.f / (1.f + __expf(-gi)), f_ = 1.f / (1.f + __expf(-gf));
                float g_ = tanhfast(gg), o_ = 1.f / (1.f + __expf(-go));
                c1 = f_ * c1 + i_ * g_; h1v = o_ * tanhfast(c1);
            }
            unsigned short hb0 = f2b(h0v), hb1 = f2b(h1v);
            unsigned pk = (unsigned)hb0 | ((unsigned)hb1 << 16);
            stU((unsigned*)(hsl + (long)(t + 1) * 65536 + (long)pb * 1024 + jg), pk);
            *(unsigned*)(enc_out + ((long)pb * 64 + t) * 1024 + jg) = pk;
            eoT[((long)pb * 1024 + jg) * 64 + t]     = hb0;
            eoT[((long)pb * 1024 + jg + 1) * 64 + t] = hb1;
            if (t < 63) {
                pr0 = *(const float4*)(pre + (long)(t + 1) * 262144 + (long)pb * 4096 + n0 + pjl * 4);
                pr1 = *(const float4*)(pre + (long)(t + 1) * 262144 + (long)pb * 4096 + n0 + pjl * 4 + 4);
            } else {
                *(unsigned*)(hS0 + (long)pb * 1024 + jg) = pk;
                cspill[(long)pb * 1024 + jg]     = c0;
                cspill[(long)pb * 1024 + jg + 1] = c1;
            }
        }
        gbar(slots, gen, ++bt);
    }
}

// ---------- persistent decoder: 2 barriers/step; q computed in-block ----------
__global__ __launch_bounds__(512, 2) void k_dec(
    const _Float16* __restrict__ Wh16,       // [col][k] fp16, 1024x1024
    const unsigned short* __restrict__ Wc,   // 4096x2048 gate-interleaved
    const float* __restrict__ pre,           // [31][64][4096]
    const _Float16* __restrict__ proj16,     // [b*64+s][1024] fp16
    const unsigned short* __restrict__ eoT,  // [b][h][t]
    const float* __restrict__ v,
    const float* __restrict__ cspill,
    unsigned short* __restrict__ hS,         // 32 slots x [64][1024]
    unsigned short* __restrict__ ctxS,       // 32 slots x [64][1024]
    unsigned short* __restrict__ fcin,       // (t*64+b) x 2048
    int* slots, int* gen)
{
    __shared__ __align__(16) unsigned short WcL[16 * 2048];  // 64 KB K-major
    __shared__ float gs[64 * 16];
    __shared__ float hv[1024], qv[1024], vv[1024];
    __shared__ float sc[64], al[64];
    const int blk = blockIdx.x, tid = threadIdx.x;
    const int lane = tid & 63, wave = tid >> 6;
    const int rt = wave >> 1, kh = wave & 1;
    const int n0 = blk * 16;
    const int grow = (rt * 16 + (lane >> 4) * 4) * 16 + (lane & 15);
    const int pb = tid >> 1, pjl = (tid & 1) * 2;
    const int jg = blk * 4 + pjl;
    for (int i = tid; i < 4096; i += 512) {
        int r = i & 15, k8 = i >> 4;
        ((bf16x8*)WcL)[k8 * 16 + r] = *(const bf16x8*)(Wc + (long)(n0 + r) * 2048 + k8 * 8);
    }
    const bf16x8* BLc = (const bf16x8*)WcL + ((long)kh * 128 + (lane >> 4)) * 16 + (lane & 15);
    if (tid < 256) {
        float4 v4 = *(const float4*)(v + tid * 4);
        *(float4*)(vv + tid * 4) = v4;
    }
    float c0 = 0.f, c1 = 0.f;
    if (tid < 128) {
        c0 = cspill[(long)pb * 1024 + jg];
        c1 = cspill[(long)pb * 1024 + jg + 1];
    }
    __syncthreads();
    int bt = 0;
    for (int t = 0; t < 31; ++t) {
        const unsigned short* hSt   = hS   + (long)t * 65536;
        const unsigned short* ctxSt = ctxS + (long)t * 65536;
        float4 pr0 = {}, pr1 = {};
        if (tid < 128) {
            pr0 = *(const float4*)(pre + (long)t * 262144 + (long)pb * 4096 + n0 + pjl * 4);
            pr1 = *(const float4*)(pre + (long)t * 262144 + (long)pb * 4096 + n0 + pjl * 4 + 4);
        }
        // ---- phase A: attention (blocks 0..63), q computed in-block
        if (blk < 64) {
            const int b = blk;
            {   // h -> LDS f32
                unsigned pk = *(const unsigned*)(hSt + (long)b * 1024 + tid * 2);
                hv[tid * 2]     = b2f((unsigned short)(pk & 0xFFFF));
                hv[tid * 2 + 1] = b2f((unsigned short)(pk >> 16));
            }
            __syncthreads();
            {   // q cols tid*2, tid*2+1 via fp16 Wh dot
                float a0 = 0.f, a1 = 0.f;
                const h16x8* w0 = (const h16x8*)(Wh16 + (long)(tid * 2) * 1024);
                const h16x8* w1 = (const h16x8*)(Wh16 + (long)(tid * 2 + 1) * 1024);
#pragma unroll 4
                for (int k8 = 0; k8 < 128; ++k8) {
                    h16x8 x0 = w0[k8], x1 = w1[k8];
                    const float* hp = hv + k8 * 8;
#pragma unroll
                    for (int j = 0; j < 8; ++j) {
                        a0 += hp[j] * (float)x0[j];
                        a1 += hp[j] * (float)x1[j];
                    }
                }
                qv[tid * 2] = a0; qv[tid * 2 + 1] = a1;
            }
            __syncthreads();
            int s = tid >> 3, part = tid & 7;
            const h16x8* pp = (const h16x8*)(proj16 + ((long)b * 64 + s) * 1024 + part * 128);
            float a_ = 0.f;
#pragma unroll 4
            for (int d = 0; d < 16; ++d) {
                h16x8 pv = pp[d];
                int h = part * 128 + d * 8;
#pragma unroll
                for (int j = 0; j < 8; ++j)
                    a_ += vv[h + j] * tanhfast(qv[h + j] + (float)pv[j]);
            }
            a_ += __shfl_xor(a_, 1);
            a_ += __shfl_xor(a_, 2);
            a_ += __shfl_xor(a_, 4);
            if (part == 0) sc[s] = a_;
            __syncthreads();
            if (tid < 64) {
                float x = sc[tid], mx = x;
                for (int o = 32; o; o >>= 1) mx = fmaxf(mx, __shfl_xor(mx, o));
                float e = __expf(x - mx), su = e;
                for (int o = 32; o; o >>= 1) su += __shfl_xor(su, o);
                al[tid] = e / su;
            }
            __syncthreads();
            int h0 = tid * 2;
            const bf16x8* ep = (const bf16x8*)(eoT + ((long)b * 1024 + h0) * 64);
            bf16x8 e[16];
#pragma unroll
            for (int c8 = 0; c8 < 16; ++c8) e[c8] = ep[c8];
            float cacc[2];
#pragma unroll
            for (int r = 0; r < 2; ++r) {
                float s_ = 0.f;
#pragma unroll
                for (int c8 = 0; c8 < 8; ++c8) {
                    bf16x8 v8 = e[r * 8 + c8];
#pragma unroll
                    for (int jj = 0; jj < 8; ++jj)
                        s_ += al[c8 * 8 + jj] * (float)v8[jj];
                }
                cacc[r] = s_;
            }
            unsigned pk0 = (unsigned)f2b(cacc[0]) | ((unsigned)f2b(cacc[1]) << 16);
            stU((unsigned*)(ctxS + (long)t * 65536 + (long)b * 1024 + h0), pk0);
            *(unsigned*)(fcin + ((long)t * 64 + b) * 2048 + 1024 + h0) = pk0;
        }
        gbar(slots, gen, ++bt);
        // ---- phase B: gates (256 blocks x 16 cols; wave = (rt, kh))
        {
            const unsigned short* Asrc = (kh ? ctxSt : hSt)
                + (long)(rt * 16 + (lane & 15)) * 1024 + (lane >> 4) * 8;
            f32x4 acc = {};
            mac16L(Asrc,       BLc,        acc);
            mac16L(Asrc + 512, BLc + 1024, acc);
            if (kh == 0) {
#pragma unroll
                for (int q = 0; q < 4; ++q) gs[grow + q * 16] = acc[q];
            }
            __syncthreads();
            if (kh == 1) {
#pragma unroll
                for (int q = 0; q < 4; ++q) atomicAdd(&gs[grow + q * 16], acc[q]);
            }
            __syncthreads();
            if (tid < 128) {
                float4 gA = *(const float4*)(gs + pb * 16 + pjl * 4);
                float4 gB = *(const float4*)(gs + pb * 16 + pjl * 4 + 4);
                float h0v, h1v;
                {
                    float gi = gA.x + pr0.x, gf = gA.y + pr0.y, gg = gA.z + pr0.z, go = gA.w + pr0.w;
                    float i_ = 1.f / (1.f + __expf(-gi)), f_ = 1.f / (1.f + __expf(-gf));
                    float g_ = tanhfast(gg), o_ = 1.f / (1.f + __expf(-go));
                    c0 = f_ * c0 + i_ * g_; h0v = o_ * tanhfast(c0);
                }
                {
                    float gi = gB.x + pr1.x, gf = gB.y + pr1.y, gg = gB.z + pr1.z, go = gB.w + pr1.w;
                    float i_ = 1.f / (1.f + __expf(-gi)), f_ = 1.f / (1.f + __expf(-gf));
                    float g_ = tanhfast(gg), o_ = 1.f / (1.f + __expf(-go));
                    c1 = f_ * c1 + i_ * g_; h1v = o_ * tanhfast(c1);
                }
                unsigned pk = (unsigned)f2b(h0v) | ((unsigned)f2b(h1v) << 16);
                stU((unsigned*)(hS + (long)(t + 1) * 65536 + (long)pb * 1024 + jg), pk);
                *(unsigned*)(fcin + ((long)t * 64 + pb) * 2048 + jg) = pk;
            }
        }
        gbar(slots, gen, ++bt);
    }
}

// ---------- launch ----------
extern "C" void kernel_launch(void* const* d_in, const int* in_sizes, int n_in,
                              void* d_out, int out_size, void* d_ws, size_t ws_size,
                              hipStream_t stream) {
    const int*   src     = (const int*)d_in[0];
    const int*   tgt     = (const int*)d_in[1];
    const float* enc_emb = (const float*)d_in[2];
    const float* dec_emb = (const float*)d_in[3];
    const float* enc_Wih = (const float*)d_in[4];
    const float* enc_Whh = (const float*)d_in[5];
    const float* enc_bih = (const float*)d_in[6];
    const float* enc_bhh = (const float*)d_in[7];
    const float* dec_Wih = (const float*)d_in[8];
    const float* dec_Whh = (const float*)d_in[9];
    const float* dec_bih = (const float*)d_in[10];
    const float* dec_bhh = (const float*)d_in[11];
    const float* attn_W  = (const float*)d_in[12];
    const float* attn_b  = (const float*)d_in[13];
    const float* vvec    = (const float*)d_in[14];
    const float* fc_W    = (const float*)d_in[15];
    const float* fc_b    = (const float*)d_in[16];
    float* out = (float*)d_out;

    char* ws = (char*)d_ws;
    size_t off = 0;
    auto alloc = [&](size_t bytes) -> char* {
        off = (off + 255) & ~(size_t)255;
        char* p = ws + off; off += bytes; return p;
    };
    unsigned short* wX      = (unsigned short*)alloc(4096UL * 512 * 2);
    unsigned short* weWih   = (unsigned short*)alloc(4096UL * 512 * 2);
    unsigned short* weWhh   = (unsigned short*)alloc(4096UL * 1024 * 2);
    float*          ebias   = (float*)alloc(4096UL * 4);
    float*          pre_enc = (float*)alloc(4096UL * 4096 * 4);
    unsigned short* enc_out = (unsigned short*)alloc(4096UL * 1024 * 2);
    unsigned short* eoT     = (unsigned short*)alloc(64UL * 1024 * 64 * 2);
    unsigned short* wWe     = (unsigned short*)alloc(1024UL * 1024 * 2);
    _Float16*       wWh16   = (_Float16*)alloc(1024UL * 1024 * 2);
    _Float16*       proj16  = (_Float16*)alloc(4096UL * 1024 * 2);
    float*          cbuf    = (float*)alloc(64UL * 1024 * 4);
    unsigned short* demb    = (unsigned short*)alloc(2048UL * 512 * 2);
    unsigned short* wDemb   = (unsigned short*)alloc(4096UL * 512 * 2);
    unsigned short* wCat    = (unsigned short*)alloc(4096UL * 2048 * 2);
    float*          dbias   = (float*)alloc(4096UL * 4);
    float*          pre_dec = (float*)alloc(2048UL * 4096 * 4);
    unsigned short* fcin    = (unsigned short*)alloc(2048UL * 2048 * 2);
    unsigned short* wFc     = (unsigned short*)alloc(32000UL * 2048 * 2);
    unsigned short* hslE    = (unsigned short*)alloc(65UL * 65536 * 2);
    unsigned short* hS      = (unsigned short*)alloc(32UL * 65536 * 2);
    unsigned short* ctxS    = (unsigned short*)alloc(32UL * 65536 * 2);
    int*            bar     = (int*)alloc(65536);
    (void)ws_size; (void)in_sizes; (void)n_in; (void)out_size;

    int* slotsE = bar;
    int* genE   = bar + 4096;
    int* slotsD = bar + 8192;
    int* genD   = bar + 12288;

    hipMemsetAsync(bar, 0, 65536, stream);
    hipMemsetAsync(hslE, 0, 65536UL * 2, stream);
    k_zero0<<<512, 256, 0, stream>>>(out);

    k_gather<<<2048, 256, 0, stream>>>(enc_emb, src, wX, 64, 64);
    k_gather<<<1024, 256, 0, stream>>>(dec_emb, tgt, demb, 31, 32);
    k_conv<<<2048, 256, 0, stream>>>(enc_Wih, weWih, 4096, 512, 512, 0, 512, 0, 1);
    k_conv<<<2048, 256, 0, stream>>>(enc_Whh, weWhh, 4096, 1024, 1024, 0, 1024, 0, 1);
    k_conv<<<2048, 256, 0, stream>>>(dec_Wih, wDemb, 4096, 512, 1536, 0, 512, 0, 1);
    k_conv<<<2048, 256, 0, stream>>>(dec_Whh, wCat, 4096, 1024, 1024, 0, 2048, 0, 1);
    k_conv<<<2048, 256, 0, stream>>>(dec_Wih, wCat, 4096, 1024, 1536, 512, 2048, 1024, 1);
    k_conv16<<<2048, 256, 0, stream>>>(attn_W, wWh16, 1024, 1024, 2048, 0);
    k_conv<<<2048, 256, 0, stream>>>(attn_W, wWe, 1024, 1024, 2048, 1024, 1024, 0, 0);
    k_conv<<<4096, 256, 0, stream>>>(fc_W, wFc, 32000, 2048, 2048, 0, 2048, 0, 0);
    k_bias<<<16, 256, 0, stream>>>(enc_bih, enc_bhh, ebias);
    k_bias<<<16, 256, 0, stream>>>(dec_bih, dec_bhh, dbias);

    // pre-gates GEMMs
    k_gemm<128,128,2,2,4,4,0><<<dim3(32, 32), 256, 0, stream>>>(
        wX, 512, weWih, 512, pre_enc, 4096, ebias, 4096, 4096, 512, 4096);
    k_gemm<128,128,2,2,4,4,0><<<dim3(32, 16), 256, 0, stream>>>(
        demb, 512, wDemb, 512, pre_dec, 4096, dbias, 2048, 4096, 512, 2048);

    // persistent encoder
    k_enc<<<256, 512, 0, stream>>>(weWhh, pre_enc, hslE, enc_out, eoT,
                                   hS, cbuf, slotsE, genE);

    // enc_proj (+attn_b) -> fp16
    k_gemm<128,128,2,2,4,4,2><<<dim3(8, 32), 256, 0, stream>>>(
        enc_out, 1024, wWe, 1024, (float*)proj16, 1024, attn_b, 4096, 1024, 1024, 4096);

    // persistent decoder (2 barriers/step)
    k_dec<<<256, 512, 0, stream>>>(wWh16, wCat, pre_dec, proj16, eoT, vvec, cbuf,
                                   hS, ctxS, fcin, slotsD, genD);

    // fc GEMM, 2-phase double-buffered, XCD-grouped
    k_fc<128,128,2,4,4><<<dim3(4096), 256, 0, stream>>>(
        fcin, 2048, wFc, 2048, out, 32000, fc_b, 2048, 1984);
}

// Round 17
// 2290.786 us; speedup vs baseline: 1.7667x; 1.7667x over previous
//
#include <hip/hip_runtime.h>
#include <hip/hip_bf16.h>

// ---------- types / helpers ----------
typedef __bf16 bf16x8 __attribute__((ext_vector_type(8)));
typedef float  f32x4  __attribute__((ext_vector_type(4)));
typedef _Float16 h16x8 __attribute__((ext_vector_type(8)));

__device__ __forceinline__ unsigned short f2b(float f) {
    union { float f; unsigned u; } w; w.f = f;
    unsigned u = w.u + 0x7FFF + ((w.u >> 16) & 1);
    return (unsigned short)(u >> 16);
}
__device__ __forceinline__ float tanhfast(float x) {
    float e = __expf(2.0f * x);
    return 1.0f - 2.0f / (e + 1.0f);
}

// AGENT-scope write-through stores for per-step state; readers plain loads
// (fresh-slot discipline).
__device__ __forceinline__ void stU(unsigned* p, unsigned v) {
    __hip_atomic_store(p, v, __ATOMIC_RELAXED, __HIP_MEMORY_SCOPE_AGENT);
}
__device__ __forceinline__ void stF(float* p, float v) {
    __hip_atomic_store(p, v, __ATOMIC_RELAXED, __HIP_MEMORY_SCOPE_AGENT);
}
__device__ __forceinline__ int ldI(const int* p) {
    return __hip_atomic_load((int*)p, __ATOMIC_RELAXED, __HIP_MEMORY_SCOPE_AGENT);
}
__device__ __forceinline__ void stI(int* p, int v) {
    __hip_atomic_store(p, v, __ATOMIC_RELAXED, __HIP_MEMORY_SCOPE_AGENT);
}

#define GLD16(g, l) __builtin_amdgcn_global_load_lds( \
    (const __attribute__((address_space(1))) void*)(g), \
    (__attribute__((address_space(3))) void*)(l), 16, 0, 0)

#define SLOT_STRIDE 16
#define NPOLL 256

// tree grid barrier (256 blocks)
__device__ __forceinline__ void gbar(int* slots, int* gen, int target) {
    asm volatile("s_waitcnt vmcnt(0)" ::: "memory");
    __syncthreads();
    if (blockIdx.x == 0) {
        if (threadIdx.x == 0) stI(slots, target);
        if (threadIdx.x < NPOLL) {
            while (ldI(slots + threadIdx.x * SLOT_STRIDE) < target)
                __builtin_amdgcn_s_sleep(1);
        }
        __syncthreads();
        if (threadIdx.x == 0) stI(gen, target);
    } else {
        if (threadIdx.x == 0) {
            stI(slots + blockIdx.x * SLOT_STRIDE, target);
            while (ldI(gen) < target)
                __builtin_amdgcn_s_sleep(1);
        }
        __syncthreads();
    }
}

// 16-deep load batch + 16 MFMAs. B from LDS K-major ([k8][16 rows] bf16x8).
__device__ __forceinline__ void mac16L(const unsigned short* A, const bf16x8* BL,
                                       f32x4& acc) {
    bf16x8 a[16];
#pragma unroll
    for (int kk = 0; kk < 16; ++kk) a[kk] = *(const bf16x8*)(A + kk * 32);
#pragma unroll
    for (int kk = 0; kk < 16; ++kk)
        acc = __builtin_amdgcn_mfma_f32_16x16x32_bf16(a[kk], BL[kk * 64], acc, 0, 0, 0);
}
__device__ __forceinline__ void mac4L(const unsigned short* A, const bf16x8* BL,
                                      f32x4& acc) {
    bf16x8 a[4];
#pragma unroll
    for (int kk = 0; kk < 4; ++kk) a[kk] = *(const bf16x8*)(A + kk * 32);
#pragma unroll
    for (int kk = 0; kk < 4; ++kk)
        acc = __builtin_amdgcn_mfma_f32_16x16x32_bf16(a[kk], BL[kk * 64], acc, 0, 0, 0);
}

// ---------- elementwise / conversion kernels ----------

// both gathers in one launch (time-major bf16 embeddings)
__global__ void k_gather2(const float* __restrict__ enc_emb, const int* __restrict__ src,
                          const float* __restrict__ dec_emb, const int* __restrict__ tgt,
                          unsigned short* __restrict__ wX, unsigned short* __restrict__ demb) {
    const long T1 = 64L * 64 * 128, T2 = 31L * 64 * 128;
    for (long i = (long)blockIdx.x * blockDim.x + threadIdx.x; i < T1 + T2;
         i += (long)gridDim.x * blockDim.x) {
        const float* emb; const int* tok; unsigned short* out; int ldtok; long j;
        if (i < T1) { emb = enc_emb; tok = src; out = wX; ldtok = 64; j = i; }
        else        { emb = dec_emb; tok = tgt; out = demb; ldtok = 32; j = i - T1; }
        int  e4 = (int)(j & 127);
        long r  = j >> 7;
        int  t  = (int)(r >> 6), b = (int)(r & 63);
        int  tk = tok[b * ldtok + t];
        float4 v = *(const float4*)(emb + (long)tk * 512 + e4 * 4);
        ushort4 o; o.x = f2b(v.x); o.y = f2b(v.y); o.z = f2b(v.z); o.w = f2b(v.w);
        *(ushort4*)(out + r * 512 + e4 * 4) = o;
    }
}

__global__ void k_conv(const float* __restrict__ in, unsigned short* __restrict__ out,
                       long N_, int K_, int ldin, int col0, int ldout, int outcol0, int reorder) {
    long total = N_ * (K_ >> 2);
    int kq = K_ >> 2;
    for (long i = (long)blockIdx.x * blockDim.x + threadIdx.x; i < total;
         i += (long)gridDim.x * blockDim.x) {
        long n = i / kq;
        int  k4 = (int)(i - n * kq) * 4;
        long row = reorder ? (long)((n & 3) * 1024 + (n >> 2)) : n;
        float4 v = *(const float4*)(in + row * ldin + col0 + k4);
        ushort4 o; o.x = f2b(v.x); o.y = f2b(v.y); o.z = f2b(v.z); o.w = f2b(v.w);
        *(ushort4*)(out + n * ldout + outcol0 + k4) = o;
    }
}

// split attn_W into wWh (cols 0..1023) and wWe (cols 1024..2047), one pass
__global__ void k_attnw(const float* __restrict__ attn_W,
                        unsigned short* __restrict__ wWh,
                        unsigned short* __restrict__ wWe) {
    long total = 1024L * 256;
    for (long i = (long)blockIdx.x * blockDim.x + threadIdx.x; i < total;
         i += (long)gridDim.x * blockDim.x) {
        long n = i >> 8;
        int  k4 = (int)(i & 255) * 4;
        float4 a = *(const float4*)(attn_W + n * 2048 + k4);
        float4 b = *(const float4*)(attn_W + n * 2048 + 1024 + k4);
        ushort4 oa; oa.x = f2b(a.x); oa.y = f2b(a.y); oa.z = f2b(a.z); oa.w = f2b(a.w);
        ushort4 ob; ob.x = f2b(b.x); ob.y = f2b(b.y); ob.z = f2b(b.z); ob.w = f2b(b.w);
        *(ushort4*)(wWh + n * 1024 + k4) = oa;
        *(ushort4*)(wWe + n * 1024 + k4) = ob;
    }
}

// both gate-bias combines in one launch
__global__ void k_bias2(const float* __restrict__ e1, const float* __restrict__ e2,
                        const float* __restrict__ d1, const float* __restrict__ d2,
                        float* __restrict__ eb, float* __restrict__ db) {
    int n = blockIdx.x * blockDim.x + threadIdx.x;
    if (n < 4096) {
        int row = (n & 3) * 1024 + (n >> 2);
        eb[n] = e1[row] + e2[row];
    } else if (n < 8192) {
        int m = n - 4096;
        int row = (m & 3) * 1024 + (m >> 2);
        db[m] = d1[row] + d2[row];
    }
}

__global__ void k_zero0(float* __restrict__ out) {
    long total = 64L * 8000;
    for (long i = (long)blockIdx.x * blockDim.x + threadIdx.x; i < total;
         i += (long)gridDim.x * blockDim.x) {
        int b = (int)(i / 8000), q = (int)(i % 8000);
        float4 z = {0.f, 0.f, 0.f, 0.f};
        *(float4*)(out + (long)b * 1024000 + q * 4) = z;
    }
}

// ---------- big-GEMM (prep + proj), m97 structure ----------
template<int BM, int BN, int WGM, int WGN, int FM, int FN>
__device__ __forceinline__ void gemm_core(
    const unsigned short* __restrict__ A, int lda,
    const unsigned short* __restrict__ B, int ldb,
    long m0, long n0, int K,
    unsigned short* As, unsigned short* Bs,
    f32x4 (&acc)[FM][FN])
{
    const int tid  = threadIdx.x;
    const int lane = tid & 63;
    const int wave = tid >> 6;
    const int wm = wave / WGN;
    const int wn = wave % WGN;
    const int srow = lane >> 2;
    const int scol = (lane & 3) * 8;
    const int frow = lane & 15;
    const int fcol = (lane >> 4) * 8;

    for (int k0 = 0; k0 < K; k0 += 32) {
        __syncthreads();
        for (int c = wave; c < BM / 16; c += 4) {
            const unsigned short* g = A + (m0 + c * 16 + srow) * (long)lda + k0 + scol;
            GLD16(g, As + c * 512);
        }
        for (int c = wave; c < BN / 16; c += 4) {
            const unsigned short* g = B + (n0 + c * 16 + srow) * (long)ldb + k0 + scol;
            GLD16(g, Bs + c * 512);
        }
        __syncthreads();
        bf16x8 af[FM], bfr[FN];
#pragma unroll
        for (int m = 0; m < FM; ++m)
            af[m] = *(const bf16x8*)(As + ((wm * FM + m) * 16 + frow) * 32 + fcol);
#pragma unroll
        for (int n = 0; n < FN; ++n)
            bfr[n] = *(const bf16x8*)(Bs + ((wn * FN + n) * 16 + frow) * 32 + fcol);
#pragma unroll
        for (int m = 0; m < FM; ++m)
#pragma unroll
            for (int n = 0; n < FN; ++n)
                acc[m][n] = __builtin_amdgcn_mfma_f32_16x16x32_bf16(af[m], bfr[n], acc[m][n], 0, 0, 0);
    }
}

// MODE 0: f32 out. MODE 2: fp16 out.
template<int BM, int BN, int WGM, int WGN, int FM, int FN, int MODE>
__global__ __launch_bounds__(256) void k_gemm(
    const unsigned short* __restrict__ A, int lda,
    const unsigned short* __restrict__ B, int ldb,
    float* __restrict__ C, long ldc, const float* __restrict__ bias,
    int M, int N, int K, int Mreal)
{
    __shared__ __align__(16) unsigned short As[BM * 32];
    __shared__ __align__(16) unsigned short Bs[BN * 32];
    long m0 = (long)blockIdx.y * BM;
    long n0 = (long)blockIdx.x * BN;
    f32x4 acc[FM][FN] = {};
    gemm_core<BM, BN, WGM, WGN, FM, FN>(A, lda, B, ldb, m0, n0, K, As, Bs, acc);

    const int lane = threadIdx.x & 63;
    const int wave = threadIdx.x >> 6;
    const int wm = wave / WGN, wn = wave % WGN;
#pragma unroll
    for (int n = 0; n < FN; ++n) {
        long col = n0 + wn * FN * 16 + n * 16 + (lane & 15);
        float bv = bias ? bias[col] : 0.0f;
#pragma unroll
        for (int m = 0; m < FM; ++m) {
            int rl = wm * FM * 16 + m * 16 + (lane >> 4) * 4;
#pragma unroll
            for (int q = 0; q < 4; ++q) {
                long r = m0 + rl + q;
                float val = acc[m][n][q] + bv;
                if (MODE == 0) {
                    C[r * ldc + col] = val;
                } else {
                    ((_Float16*)C)[r * ldc + col] = (_Float16)val;
                }
            }
        }
    }
}

// ---------- fc GEMM: 2-phase double-buffered, XCD-grouped ----------
template<int BM, int BN, int WGN, int FM, int FN>
__global__ __launch_bounds__(256) void k_fc(
    const unsigned short* __restrict__ A, int lda,
    const unsigned short* __restrict__ B, int ldb,
    float* __restrict__ C, long ldc, const float* __restrict__ bias,
    int K, int Mreal)
{
    __shared__ __align__(16) unsigned short As[2][BM * 32];
    __shared__ __align__(16) unsigned short Bs[2][BN * 32];
    int bid = blockIdx.x;
    int n = (bid & 7) * 32 + (bid >> 7);
    int m = (bid >> 3) & 15;
    if (n >= 250) return;
    long m0 = (long)m * BM, n0 = (long)n * BN;
    const int tid = threadIdx.x, lane = tid & 63, wave = tid >> 6;
    const int wm = wave / WGN, wn = wave % WGN;
    const int srow = lane >> 2, scol = (lane & 3) * 8;
    const int frow = lane & 15, fcol = (lane >> 4) * 8;
    f32x4 acc[FM][FN] = {};

#define FC_STAGE(buf, k0) \
    { for (int c = wave; c < BM / 16; c += 4) \
          GLD16(A + (m0 + c * 16 + srow) * (long)lda + (k0) + scol, As[buf] + c * 512); \
      for (int c = wave; c < BN / 16; c += 4) \
          GLD16(B + (n0 + c * 16 + srow) * (long)ldb + (k0) + scol, Bs[buf] + c * 512); }

    FC_STAGE(0, 0);
    asm volatile("s_waitcnt vmcnt(0)" ::: "memory");
    __syncthreads();
    const int NT = K / 32;
    for (int t = 0; t < NT; ++t) {
        int cur = t & 1;
        if (t + 1 < NT) FC_STAGE(cur ^ 1, (t + 1) * 32);
        bf16x8 af[FM], bfr[FN];
#pragma unroll
        for (int mm = 0; mm < FM; ++mm)
            af[mm] = *(const bf16x8*)(As[cur] + ((wm * FM + mm) * 16 + frow) * 32 + fcol);
#pragma unroll
        for (int nn = 0; nn < FN; ++nn)
            bfr[nn] = *(const bf16x8*)(Bs[cur] + ((wn * FN + nn) * 16 + frow) * 32 + fcol);
#pragma unroll
        for (int mm = 0; mm < FM; ++mm)
#pragma unroll
            for (int nn = 0; nn < FN; ++nn)
                acc[mm][nn] = __builtin_amdgcn_mfma_f32_16x16x32_bf16(af[mm], bfr[nn], acc[mm][nn], 0, 0, 0);
        asm volatile("s_waitcnt vmcnt(0)" ::: "memory");
        __syncthreads();
    }
#undef FC_STAGE
#pragma unroll
    for (int nn = 0; nn < FN; ++nn) {
        long col = n0 + wn * FN * 16 + nn * 16 + (lane & 15);
        float bv = bias[col];
#pragma unroll
        for (int mm = 0; mm < FM; ++mm) {
            int rl = wm * FM * 16 + mm * 16 + (lane >> 4) * 4;
#pragma unroll
            for (int q = 0; q < 4; ++q) {
                long r = m0 + rl + q;
                if (r < Mreal) {
                    long orow = (r & 63) * 32 + (r >> 6) + 1;
                    C[orow * ldc + col] = acc[mm][nn][q] + bv;
                }
            }
        }
    }
}

// ---------- persistent encoder: 256 blocks x 512 threads; W slice in LDS ----------
__global__ __launch_bounds__(512, 2) void k_enc(
    const unsigned short* __restrict__ W,
    const float* __restrict__ pre,
    unsigned short* __restrict__ hsl,
    unsigned short* __restrict__ enc_out,
    unsigned short* __restrict__ eoT,
    unsigned short* __restrict__ hS0,
    float* __restrict__ cspill,
    int* slots, int* gen)
{
    __shared__ __align__(16) unsigned short WL[16 * 1024];
    __shared__ float gs[64 * 16];
    const int blk = blockIdx.x, tid = threadIdx.x;
    const int lane = tid & 63, wave = tid >> 6;
    const int rt = wave >> 1, kh = wave & 1;
    const int n0 = blk * 16;
    const int grow = (rt * 16 + (lane >> 4) * 4) * 16 + (lane & 15);
    const int pb = tid >> 1, pjl = (tid & 1) * 2;
    const int jg = blk * 4 + pjl;
    for (int i = tid; i < 2048; i += 512) {
        int r = i & 15, k8 = i >> 4;
        ((bf16x8*)WL)[k8 * 16 + r] = *(const bf16x8*)(W + (long)(n0 + r) * 1024 + k8 * 8);
    }
    const bf16x8* BL = (const bf16x8*)WL + ((long)kh * 64 + (lane >> 4)) * 16 + (lane & 15);
    float c0 = 0.f, c1 = 0.f;
    float4 pr0 = {}, pr1 = {};
    if (tid < 128) {
        pr0 = *(const float4*)(pre + (long)pb * 4096 + n0 + pjl * 4);
        pr1 = *(const float4*)(pre + (long)pb * 4096 + n0 + pjl * 4 + 4);
    }
    __syncthreads();
    int bt = 0;
    for (int t = 0; t < 64; ++t) {
        const unsigned short* Ar = hsl + (long)t * 65536
            + (long)(rt * 16 + (lane & 15)) * 1024 + kh * 512 + (lane >> 4) * 8;
        f32x4 acc = {};
        mac16L(Ar, BL, acc);
        if (kh == 0) {
#pragma unroll
            for (int q = 0; q < 4; ++q) gs[grow + q * 16] = acc[q];
        }
        __syncthreads();
        if (kh == 1) {
#pragma unroll
            for (int q = 0; q < 4; ++q) atomicAdd(&gs[grow + q * 16], acc[q]);
        }
        __syncthreads();
        if (tid < 128) {
            float4 gA = *(const float4*)(gs + pb * 16 + pjl * 4);
            float4 gB = *(const float4*)(gs + pb * 16 + pjl * 4 + 4);
            float h0v, h1v;
            {
                float gi = gA.x + pr0.x, gf = gA.y + pr0.y, gg = gA.z + pr0.z, go = gA.w + pr0.w;
                float i_ = 1.f / (1.f + __expf(-gi)), f_ = 1.f / (1.f + __expf(-gf));
                float g_ = tanhfast(gg), o_ = 1.f / (1.f + __expf(-go));
                c0 = f_ * c0 + i_ * g_; h0v = o_ * tanhfast(c0);
            }
            {
                float gi = gB.x + pr1.x, gf = gB.y + pr1.y, gg = gB.z + pr1.z, go = gB.w + pr1.w;
                float i_ = 1.f / (1.f + __expf(-gi)), f_ = 1.f / (1.f + __expf(-gf));
                float g_ = tanhfast(gg), o_ = 1.f / (1.f + __expf(-go));
                c1 = f_ * c1 + i_ * g_; h1v = o_ * tanhfast(c1);
            }
            unsigned short hb0 = f2b(h0v), hb1 = f2b(h1v);
            unsigned pk = (unsigned)hb0 | ((unsigned)hb1 << 16);
            stU((unsigned*)(hsl + (long)(t + 1) * 65536 + (long)pb * 1024 + jg), pk);
            *(unsigned*)(enc_out + ((long)pb * 64 + t) * 1024 + jg) = pk;
            eoT[((long)pb * 1024 + jg) * 64 + t]     = hb0;
            eoT[((long)pb * 1024 + jg + 1) * 64 + t] = hb1;
            if (t < 63) {
                pr0 = *(const float4*)(pre + (long)(t + 1) * 262144 + (long)pb * 4096 + n0 + pjl * 4);
                pr1 = *(const float4*)(pre + (long)(t + 1) * 262144 + (long)pb * 4096 + n0 + pjl * 4 + 4);
            } else {
                *(unsigned*)(hS0 + (long)pb * 1024 + jg) = pk;
                cspill[(long)pb * 1024 + jg]     = c0;
                cspill[(long)pb * 1024 + jg + 1] = c1;
            }
        }
        gbar(slots, gen, ++bt);
    }
}

// ---------- persistent decoder: Wc + Wh slices in LDS; attn spread 256-wide ----------
__global__ __launch_bounds__(512, 2) void k_dec(
    const unsigned short* __restrict__ Wh,
    const unsigned short* __restrict__ Wc,
    const float* __restrict__ pre,
    const _Float16* __restrict__ proj16,
    const unsigned short* __restrict__ eoT,
    const float* __restrict__ v,
    const float* __restrict__ cspill,
    unsigned short* __restrict__ hS,
    unsigned short* __restrict__ ctxS,
    float* __restrict__ qS,
    unsigned short* __restrict__ fcin,
    int* slots, int* gen)
{
    __shared__ __align__(16) unsigned short WcL[16 * 2048];  // 64 KB K-major
    __shared__ __align__(16) unsigned short WhL[16 * 1024];  // 32 KB K-major
    __shared__ float gs[64 * 16];
    __shared__ float qv[1024], vv[1024];
    __shared__ float sc[64], al[64];
    const int blk = blockIdx.x, tid = threadIdx.x;
    const int lane = tid & 63, wave = tid >> 6;
    const int rt = wave >> 1, kh = wave & 1;
    const int n0 = blk * 16;
    const int nq = blk >> 2, mt = blk & 3;
    const int ab = blk >> 2, qt = blk & 3;   // attention: batch row, h-quarter
    const int grow = (rt * 16 + (lane >> 4) * 4) * 16 + (lane & 15);
    const int pb = tid >> 1, pjl = (tid & 1) * 2;
    const int jg = blk * 4 + pjl;
    for (int i = tid; i < 4096; i += 512) {
        int r = i & 15, k8 = i >> 4;
        ((bf16x8*)WcL)[k8 * 16 + r] = *(const bf16x8*)(Wc + (long)(n0 + r) * 2048 + k8 * 8);
    }
    for (int i = tid; i < 2048; i += 512) {
        int r = i & 15, k8 = i >> 4;
        ((bf16x8*)WhL)[k8 * 16 + r] = *(const bf16x8*)(Wh + (long)(nq * 16 + r) * 1024 + k8 * 8);
    }
    const bf16x8* BLc = (const bf16x8*)WcL + ((long)kh * 128 + (lane >> 4)) * 16 + (lane & 15);
    const bf16x8* BLq = (const bf16x8*)WhL + ((long)wave * 16 + (lane >> 4)) * 16 + (lane & 15);
    if (tid < 256) {
        float4 v4 = *(const float4*)(v + tid * 4);
        *(float4*)(vv + tid * 4) = v4;
    }
    float c0 = 0.f, c1 = 0.f;
    if (tid < 128) {
        c0 = cspill[(long)pb * 1024 + jg];
        c1 = cspill[(long)pb * 1024 + jg + 1];
    }
    __syncthreads();
    int bt = 0;
    for (int t = 0; t < 31; ++t) {
        const unsigned short* hSt   = hS   + (long)t * 65536;
        const unsigned short* ctxSt = ctxS + (long)t * 65536;
        float4 pr0 = {}, pr1 = {};
        if (tid < 128) {
            pr0 = *(const float4*)(pre + (long)t * 262144 + (long)pb * 4096 + n0 + pjl * 4);
            pr1 = *(const float4*)(pre + (long)t * 262144 + (long)pb * 4096 + n0 + pjl * 4 + 4);
        }
        // ---- phase 1: q = h_t @ Wh^T (64 n-tiles x 4 m-tiles; 8-way K split)
        {
            if (tid < 256) gs[tid] = 0.f;
            __syncthreads();
            const unsigned short* Ar = hSt + (long)(mt * 16 + (lane & 15)) * 1024
                                           + wave * 128 + (lane >> 4) * 8;
            f32x4 qa = {};
            mac4L(Ar, BLq, qa);
#pragma unroll
            for (int q = 0; q < 4; ++q)
                atomicAdd(&gs[((lane >> 4) * 4 + q) * 16 + (lane & 15)], qa[q]);
            __syncthreads();
            if (tid < 256)
                stF(qS + (long)t * 65536 + (long)(mt * 16 + (tid >> 4)) * 1024
                        + nq * 16 + (tid & 15), gs[tid]);
        }
        gbar(slots, gen, ++bt);
        // ---- phase 2: attention, ALL 256 blocks (b = blk>>2, h-quarter = blk&3)
        {
            const int b = ab;
            if (tid < 256)
                *(float4*)(qv + tid * 4) =
                    *(const float4*)(qS + (long)t * 65536 + (long)b * 1024 + tid * 4);
            __syncthreads();
            // scores (redundant across the 4 quarter-blocks; cheap)
            int s = tid >> 3, part = tid & 7;
            const h16x8* pp = (const h16x8*)(proj16 + ((long)b * 64 + s) * 1024 + part * 128);
            float a_ = 0.f;
#pragma unroll 4
            for (int d = 0; d < 16; ++d) {
                h16x8 pv = pp[d];
                int h = part * 128 + d * 8;
#pragma unroll
                for (int j = 0; j < 8; ++j)
                    a_ += vv[h + j] * tanhfast(qv[h + j] + (float)pv[j]);
            }
            a_ += __shfl_xor(a_, 1);
            a_ += __shfl_xor(a_, 2);
            a_ += __shfl_xor(a_, 4);
            if (part == 0) sc[s] = a_;
            __syncthreads();
            if (tid < 64) {
                float x = sc[tid], mx = x;
                for (int o = 32; o; o >>= 1) mx = fmaxf(mx, __shfl_xor(mx, o));
                float e = __expf(x - mx), su = e;
                for (int o = 32; o; o >>= 1) su += __shfl_xor(su, o);
                al[tid] = e / su;
            }
            __syncthreads();
            if (tid < 128) {
                int h0 = qt * 256 + tid * 2;   // this block's h-quarter
                const bf16x8* ep = (const bf16x8*)(eoT + ((long)b * 1024 + h0) * 64);
                bf16x8 e[16];
#pragma unroll
                for (int c8 = 0; c8 < 16; ++c8) e[c8] = ep[c8];
                float cacc[2];
#pragma unroll
                for (int r = 0; r < 2; ++r) {
                    float s_ = 0.f;
#pragma unroll
                    for (int c8 = 0; c8 < 8; ++c8) {
                        bf16x8 v8 = e[r * 8 + c8];
#pragma unroll
                        for (int jj = 0; jj < 8; ++jj)
                            s_ += al[c8 * 8 + jj] * (float)v8[jj];
                    }
                    cacc[r] = s_;
                }
                unsigned pk0 = (unsigned)f2b(cacc[0]) | ((unsigned)f2b(cacc[1]) << 16);
                stU((unsigned*)(ctxS + (long)t * 65536 + (long)b * 1024 + h0), pk0);
                *(unsigned*)(fcin + ((long)t * 64 + b) * 2048 + 1024 + h0) = pk0;
            }
        }
        gbar(slots, gen, ++bt);
        // ---- phase 3: gates (256 blocks x 16 cols; wave = (rt, kh); kh0=h, kh1=ctx)
        {
            const unsigned short* Asrc = (kh ? ctxSt : hSt)
                + (long)(rt * 16 + (lane & 15)) * 1024 + (lane >> 4) * 8;
            f32x4 acc = {};
            mac16L(Asrc,       BLc,        acc);
            mac16L(Asrc + 512, BLc + 1024, acc);
            if (kh == 0) {
#pragma unroll
                for (int q = 0; q < 4; ++q) gs[grow + q * 16] = acc[q];
            }
            __syncthreads();
            if (kh == 1) {
#pragma unroll
                for (int q = 0; q < 4; ++q) atomicAdd(&gs[grow + q * 16], acc[q]);
            }
            __syncthreads();
            if (tid < 128) {
                float4 gA = *(const float4*)(gs + pb * 16 + pjl * 4);
                float4 gB = *(const float4*)(gs + pb * 16 + pjl * 4 + 4);
                float h0v, h1v;
                {
                    float gi = gA.x + pr0.x, gf = gA.y + pr0.y, gg = gA.z + pr0.z, go = gA.w + pr0.w;
                    float i_ = 1.f / (1.f + __expf(-gi)), f_ = 1.f / (1.f + __expf(-gf));
                    float g_ = tanhfast(gg), o_ = 1.f / (1.f + __expf(-go));
                    c0 = f_ * c0 + i_ * g_; h0v = o_ * tanhfast(c0);
                }
                {
                    float gi = gB.x + pr1.x, gf = gB.y + pr1.y, gg = gB.z + pr1.z, go = gB.w + pr1.w;
                    float i_ = 1.f / (1.f + __expf(-gi)), f_ = 1.f / (1.f + __expf(-gf));
                    float g_ = tanhfast(gg), o_ = 1.f / (1.f + __expf(-go));
                    c1 = f_ * c1 + i_ * g_; h1v = o_ * tanhfast(c1);
                }
                unsigned pk = (unsigned)f2b(h0v) | ((unsigned)f2b(h1v) << 16);
                stU((unsigned*)(hS + (long)(t + 1) * 65536 + (long)pb * 1024 + jg), pk);
                *(unsigned*)(fcin + ((long)t * 64 + pb) * 2048 + jg) = pk;
            }
        }
        gbar(slots, gen, ++bt);
    }
}

// ---------- launch ----------
extern "C" void kernel_launch(void* const* d_in, const int* in_sizes, int n_in,
                              void* d_out, int out_size, void* d_ws, size_t ws_size,
                              hipStream_t stream) {
    const int*   src     = (const int*)d_in[0];
    const int*   tgt     = (const int*)d_in[1];
    const float* enc_emb = (const float*)d_in[2];
    const float* dec_emb = (const float*)d_in[3];
    const float* enc_Wih = (const float*)d_in[4];
    const float* enc_Whh = (const float*)d_in[5];
    const float* enc_bih = (const float*)d_in[6];
    const float* enc_bhh = (const float*)d_in[7];
    const float* dec_Wih = (const float*)d_in[8];
    const float* dec_Whh = (const float*)d_in[9];
    const float* dec_bih = (const float*)d_in[10];
    const float* dec_bhh = (const float*)d_in[11];
    const float* attn_W  = (const float*)d_in[12];
    const float* attn_b  = (const float*)d_in[13];
    const float* vvec    = (const float*)d_in[14];
    const float* fc_W    = (const float*)d_in[15];
    const float* fc_b    = (const float*)d_in[16];
    float* out = (float*)d_out;

    char* ws = (char*)d_ws;
    size_t off = 0;
    auto alloc = [&](size_t bytes) -> char* {
        off = (off + 255) & ~(size_t)255;
        char* p = ws + off; off += bytes; return p;
    };
    unsigned short* wX      = (unsigned short*)alloc(4096UL * 512 * 2);
    unsigned short* weWih   = (unsigned short*)alloc(4096UL * 512 * 2);
    unsigned short* weWhh   = (unsigned short*)alloc(4096UL * 1024 * 2);
    float*          ebias   = (float*)alloc(4096UL * 4);
    float*          pre_enc = (float*)alloc(4096UL * 4096 * 4);
    unsigned short* enc_out = (unsigned short*)alloc(4096UL * 1024 * 2);
    unsigned short* eoT     = (unsigned short*)alloc(64UL * 1024 * 64 * 2);
    unsigned short* wWe     = (unsigned short*)alloc(1024UL * 1024 * 2);
    unsigned short* wWh     = (unsigned short*)alloc(1024UL * 1024 * 2);
    _Float16*       proj16  = (_Float16*)alloc(4096UL * 1024 * 2);
    float*          cbuf    = (float*)alloc(64UL * 1024 * 4);
    unsigned short* demb    = (unsigned short*)alloc(2048UL * 512 * 2);
    unsigned short* wDemb   = (unsigned short*)alloc(4096UL * 512 * 2);
    unsigned short* wCat    = (unsigned short*)alloc(4096UL * 2048 * 2);
    float*          dbias   = (float*)alloc(4096UL * 4);
    float*          pre_dec = (float*)alloc(2048UL * 4096 * 4);
    unsigned short* fcin    = (unsigned short*)alloc(2048UL * 2048 * 2);
    unsigned short* wFc     = (unsigned short*)alloc(32000UL * 2048 * 2);
    unsigned short* hslE    = (unsigned short*)alloc(65UL * 65536 * 2);
    unsigned short* hS      = (unsigned short*)alloc(32UL * 65536 * 2);
    unsigned short* ctxS    = (unsigned short*)alloc(32UL * 65536 * 2);
    float*          qS      = (float*)alloc(32UL * 65536 * 4);
    int*            bar     = (int*)alloc(65536);
    (void)ws_size; (void)in_sizes; (void)n_in; (void)out_size;

    int* slotsE = bar;
    int* genE   = bar + 4096;
    int* slotsD = bar + 8192;
    int* genD   = bar + 12288;

    hipMemsetAsync(bar, 0, 65536, stream);
    hipMemsetAsync(hslE, 0, 65536UL * 2, stream);
    k_zero0<<<512, 256, 0, stream>>>(out);

    k_gather2<<<2048, 256, 0, stream>>>(enc_emb, src, dec_emb, tgt, wX, demb);
    k_conv<<<2048, 256, 0, stream>>>(enc_Wih, weWih, 4096, 512, 512, 0, 512, 0, 1);
    k_conv<<<2048, 256, 0, stream>>>(enc_Whh, weWhh, 4096, 1024, 1024, 0, 1024, 0, 1);
    k_conv<<<2048, 256, 0, stream>>>(dec_Wih, wDemb, 4096, 512, 1536, 0, 512, 0, 1);
    k_conv<<<2048, 256, 0, stream>>>(dec_Whh, wCat, 4096, 1024, 1024, 0, 2048, 0, 1);
    k_conv<<<2048, 256, 0, stream>>>(dec_Wih, wCat, 4096, 1024, 1536, 512, 2048, 1024, 1);
    k_attnw<<<2048, 256, 0, stream>>>(attn_W, wWh, wWe);
    k_conv<<<4096, 256, 0, stream>>>(fc_W, wFc, 32000, 2048, 2048, 0, 2048, 0, 0);
    k_bias2<<<32, 256, 0, stream>>>(enc_bih, enc_bhh, dec_bih, dec_bhh, ebias, dbias);

    // pre-gates GEMMs
    k_gemm<128,128,2,2,4,4,0><<<dim3(32, 32), 256, 0, stream>>>(
        wX, 512, weWih, 512, pre_enc, 4096, ebias, 4096, 4096, 512, 4096);
    k_gemm<128,128,2,2,4,4,0><<<dim3(32, 16), 256, 0, stream>>>(
        demb, 512, wDemb, 512, pre_dec, 4096, dbias, 2048, 4096, 512, 2048);

    // persistent encoder
    k_enc<<<256, 512, 0, stream>>>(weWhh, pre_enc, hslE, enc_out, eoT,
                                   hS, cbuf, slotsE, genE);

    // enc_proj (+attn_b) -> fp16
    k_gemm<128,128,2,2,4,4,2><<<dim3(8, 32), 256, 0, stream>>>(
        enc_out, 1024, wWe, 1024, (float*)proj16, 1024, attn_b, 4096, 1024, 1024, 4096);

    // persistent decoder (attn spread over all 256 blocks, tree barrier)
    k_dec<<<256, 512, 0, stream>>>(wWh, wCat, pre_dec, proj16, eoT, vvec, cbuf,
                                   hS, ctxS, qS, fcin, slotsD, genD);

    // fc GEMM, 2-phase double-buffered, XCD-grouped
    k_fc<128,128,2,4,4><<<dim3(4096), 256, 0, stream>>>(
        fcin, 2048, wFc, 2048, out, 32000, fc_b, 2048, 1984);
}